// Round 4
// baseline (485.072 us; speedup 1.0000x reference)
//
#include <hip/hip_runtime.h>
#include <hip/hip_bf16.h>

// minLSTM: pre = x @ W^T + b (M=32768, N=1536, K=512), log-space gates,
// chunked log-space scan over L=4096 per (n,h), out = exp(log_h).
// Inputs detected fp32-vs-bf16 on device; normalized to bf16 for MFMA.

#define H_DIM 512
#define LSEQ 4096
#define NBATCH 8
#define M_TOTAL (NBATCH * LSEQ)  // 32768

#define BM 128
#define BK 64

#define CS 128
#define NC 32            // LSEQ / CS

typedef __attribute__((ext_vector_type(8))) short short8;
typedef __attribute__((ext_vector_type(4))) float floatx4;
typedef _Float16 h2 __attribute__((ext_vector_type(2)));

#define NEG_BIG (-1.0e30f)

__device__ __forceinline__ float softplus_f(float z) {
    return fmaxf(z, 0.0f) + __logf(1.0f + __expf(-fabsf(z)));
}

__device__ __forceinline__ float logaddexp_f(float p, float q) {
    float m = fmaxf(p, q);
    float d = -fabsf(p - q);
    return m + __logf(1.0f + __expf(d));
}

__device__ __forceinline__ float bf16u_to_f(unsigned short u) {
    unsigned int w = ((unsigned int)u) << 16;
    float f;
    __builtin_memcpy(&f, &w, 4);
    return f;
}

__device__ __forceinline__ unsigned short f_to_bf16u(float f) {
    __hip_bfloat16 h = __float2bfloat16(f);
    unsigned short u;
    __builtin_memcpy(&u, &h, 2);
    return u;
}

__device__ __forceinline__ void gload_lds16(const void* g, void* l) {
    __builtin_amdgcn_global_load_lds(
        (const __attribute__((address_space(1))) unsigned int*)g,
        (__attribute__((address_space(3))) unsigned int*)l, 16, 0, 0);
}

// ---------------------------------------------------------------------------
// Kernel 0 (fused): per-block self-detection of input dtype (fp32 vs bf16)
// from the same L2-hot 32KB sample of x, then role by blockIdx:
//   [0, 8192)      convert x (8 elems/thread)
//   [8192, 8576)   convert W
//   8576           bias -> f32, publish flag
// fp32 data: low u16 halves uniform -> bf16-NaN exponent P=1/256,
// E[hits in 16384] = 64; bf16 N(0,1) data: 0 hits. Threshold 8.
// ---------------------------------------------------------------------------
__global__ __launch_bounds__(256)
void fused_convert(const void* __restrict__ x, const void* __restrict__ W,
                   const void* __restrict__ bsrc,
                   unsigned short* __restrict__ xc,
                   unsigned short* __restrict__ Wc,
                   float* __restrict__ bdst,
                   int* __restrict__ flagOut) {
    const unsigned short* xu = (const unsigned short*)x;
    __shared__ int cnt;
    if (threadIdx.x == 0) cnt = 0;
    __syncthreads();
    int local = 0;
    for (int i = threadIdx.x; i < 16384; i += 256) {
        unsigned short u = xu[i];
        if (((u >> 7) & 0xFF) == 0xFF) local++;
    }
    if (local) atomicAdd(&cnt, local);
    __syncthreads();
    const int flag = (cnt > 8) ? 1 : 0;

    const int bx = blockIdx.x;
    if (bx < 8192) {                       // x: 16777216 elems
        int i = (bx * 256 + threadIdx.x) * 8;
        if (flag) {
            const float* s = (const float*)x;
            short8 v;
            #pragma unroll
            for (int j = 0; j < 8; j++) v[j] = (short)f_to_bf16u(s[i + j]);
            *(short8*)&xc[i] = v;
        } else {
            *(short8*)&xc[i] = *(const short8*)&((const short*)x)[i];
        }
    } else if (bx < 8576) {                // W: 786432 elems
        int i = ((bx - 8192) * 256 + threadIdx.x) * 8;
        if (flag) {
            const float* s = (const float*)W;
            short8 v;
            #pragma unroll
            for (int j = 0; j < 8; j++) v[j] = (short)f_to_bf16u(s[i + j]);
            *(short8*)&Wc[i] = v;
        } else {
            *(short8*)&Wc[i] = *(const short8*)&((const short*)W)[i];
        }
    } else {                               // bias + flag
        for (int i = threadIdx.x; i < 3 * H_DIM; i += 256)
            bdst[i] = flag ? ((const float*)bsrc)[i]
                           : bf16u_to_f(((const unsigned short*)bsrc)[i]);
        if (threadIdx.x == 0) flagOut[0] = flag;
    }
}

// ---------------------------------------------------------------------------
// Kernel 1: GEMM + fused gate math (m97 structure + XOR-swizzled LDS).
// Block 256 = 4 waves in 2x2: wave (wr, wc2) covers rows wr..wr+63,
// nt tiles {g*4 + wc2*2 + jj}. global_load_lds width-16 staging.
// LDS swizzle: column seg' = seg ^ (row & 7); the staging lane fetches the
// xor'd global seg so LDS dest stays lane-contiguous; fragment reads xor
// the column by (row & 7) -> 2 lanes/bank (free) instead of 16-way.
// Output: packed (lf, lv) as f16x2 per element.
// ---------------------------------------------------------------------------
__global__ __launch_bounds__(256, 4)
void gemm_gates(const unsigned short* __restrict__ x,
                const unsigned short* __restrict__ W,
                const float* __restrict__ bias,
                h2* __restrict__ plv) {
    __shared__ short Alds[BM * BK];        // 16 KB
    __shared__ short Blds[192 * BK];       // 24 KB

    const int bx = blockIdx.x;             // col block 0..7 (64 cols/gate)
    const int by = blockIdx.y;             // row block 0..255
    const int tid = threadIdx.x;
    const int lane = tid & 63;
    const int w = tid >> 6;
    const int wr = (w >> 1) * 64;
    const int wc2 = w & 1;
    const int l8 = lane >> 3, s8 = lane & 7;
    const int sg = s8 ^ l8;                // swizzled global seg for staging
    const int fr = lane & 15;
    const int q = lane >> 4;

    const int R0 = by * BM;

    floatx4 acc[4][6];
    #pragma unroll
    for (int i = 0; i < 4; i++)
        #pragma unroll
        for (int j = 0; j < 6; j++)
            acc[i][j] = (floatx4){0.f, 0.f, 0.f, 0.f};

    const short* xg = (const short*)x;
    const short* wg = (const short*)W;

    for (int k0 = 0; k0 < H_DIM; k0 += BK) {
        __syncthreads();
        // A: 16 chunks of 8 rows; lane fetches global seg (s8 ^ l8)
        #pragma unroll
        for (int i = 0; i < 4; i++) {
            int c = w * 4 + i;
            const short* g = xg + (size_t)(R0 + c * 8 + l8) * H_DIM + k0 + sg * 8;
            gload_lds16(g, &Alds[c * 512]);
        }
        // B: 24 chunks of 8 rows; row br -> W row (br>>6)*512 + bx*64 + (br&63)
        #pragma unroll
        for (int i = 0; i < 6; i++) {
            int c = w * 6 + i;
            int br = c * 8 + l8;
            int wrow = (br >> 6) * H_DIM + bx * 64 + (br & 63);
            const short* g = wg + (size_t)wrow * H_DIM + k0 + sg * 8;
            gload_lds16(g, &Blds[c * 512]);
        }
        __syncthreads();

        #pragma unroll
        for (int ks = 0; ks < 2; ks++) {
            const int s = ks * 4 + q;       // k-seg index
            short8 af[4], bf[6];
            #pragma unroll
            for (int mt = 0; mt < 4; mt++) {
                int ar = wr + mt * 16 + fr;
                af[mt] = *(const short8*)&Alds[ar * BK + ((s ^ (ar & 7)) << 3)];
            }
            #pragma unroll
            for (int j = 0; j < 6; j++) {
                int nt = (j >> 1) * 4 + wc2 * 2 + (j & 1);
                int brr = nt * 16 + fr;
                bf[j] = *(const short8*)&Blds[brr * BK + ((s ^ (brr & 7)) << 3)];
            }
            #pragma unroll
            for (int mt = 0; mt < 4; mt++)
                #pragma unroll
                for (int j = 0; j < 6; j++)
                    acc[mt][j] = __builtin_amdgcn_mfma_f32_16x16x32_bf16(
                        af[mt], bf[j], acc[mt][j], 0, 0, 0);
        }
    }

    // Epilogue: C/D layout col=lane&15, row=quad*4+reg [m89/m91].
    // li = -sp(-diff) = diff - sp(diff) = diff + lf  (saves one softplus)
    const int rowb = R0 + wr + q * 4;
    #pragma unroll
    for (int jj = 0; jj < 2; jj++) {
        int hcol = bx * 64 + wc2 * 32 + jj * 16 + fr;
        float bfv = bias[hcol];
        float biv = bias[H_DIM + hcol];
        float bhv = bias[2 * H_DIM + hcol];
        #pragma unroll
        for (int mt = 0; mt < 4; mt++) {
            #pragma unroll
            for (int r = 0; r < 4; r++) {
                float fp = acc[mt][jj][r] + bfv;
                float ip = acc[mt][2 + jj][r] + biv;
                float hp = acc[mt][4 + jj][r] + bhv;
                float diff = softplus_f(-fp) - softplus_f(-ip);
                float lf = -softplus_f(diff);            // log f'
                float li = diff + lf;                    // log i'
                float lg = (hp >= 0.f) ? __logf(hp + 0.5f) : -softplus_f(-hp);
                float lv = li + lg;
                int row = rowb + mt * 16 + r;
                h2 pk;
                pk[0] = (_Float16)lf;
                pk[1] = (_Float16)lv;
                plv[(size_t)row * H_DIM + hcol] = pk;
            }
        }
    }
}

// ---------------------------------------------------------------------------
// Kernel 2: per-chunk summary. A_c = sum(log_f), B_c = chunk-local scan
// ---------------------------------------------------------------------------
__global__ __launch_bounds__(256)
void scan_chunks(const h2* __restrict__ plv,
                 float* __restrict__ Asum, float* __restrict__ Bval) {
    int h = blockIdx.x * 256 + threadIdx.x;
    int c = blockIdx.y;
    int n = blockIdx.z;
    size_t base = ((size_t)n * LSEQ + (size_t)c * CS) * H_DIM + h;
    float a = 0.f;
    float bacc = NEG_BIG;
    #pragma unroll 4
    for (int t = 0; t < CS; t++) {
        h2 p = plv[base + (size_t)t * H_DIM];
        float f = (float)p[0];
        float v = (float)p[1];
        bacc = logaddexp_f(f + bacc, v);
        a += f;
    }
    size_t o = ((size_t)n * NC + c) * H_DIM + h;
    Asum[o] = a;
    Bval[o] = bacc;
}

// ---------------------------------------------------------------------------
// Kernel 3: recompute carry from chunk summaries (<=31 logaddexp steps),
// then replay chunk and write exp(log_h) (dtype per flag).
// ---------------------------------------------------------------------------
__global__ __launch_bounds__(256)
void scan_apply(const h2* __restrict__ plv,
                const float* __restrict__ Asum, const float* __restrict__ Bval,
                void* __restrict__ outv, const int* __restrict__ flag) {
    int h = blockIdx.x * 256 + threadIdx.x;
    int c = blockIdx.y;
    int n = blockIdx.z;
    const int f32out = *flag;

    float r = -13.815510558f;  // log(1e-6)
    size_t so = (size_t)n * NC * H_DIM + h;
    for (int cp = 0; cp < c; cp++)
        r = logaddexp_f(Asum[so + (size_t)cp * H_DIM] + r,
                        Bval[so + (size_t)cp * H_DIM]);

    size_t base = ((size_t)n * LSEQ + (size_t)c * CS) * H_DIM + h;
    float* of = (float*)outv;
    __hip_bfloat16* ob = (__hip_bfloat16*)outv;
    #pragma unroll 4
    for (int t = 0; t < CS; t++) {
        h2 p = plv[base + (size_t)t * H_DIM];
        r = logaddexp_f((float)p[0] + r, (float)p[1]);
        float hval = __expf(r);
        size_t idx = base + (size_t)t * H_DIM;
        if (f32out) of[idx] = hval;
        else        ob[idx] = __float2bfloat16(hval);
    }
}

extern "C" void kernel_launch(void* const* d_in, const int* in_sizes, int n_in,
                              void* d_out, int out_size, void* d_ws, size_t ws_size,
                              hipStream_t stream) {
    const void* x = d_in[0];
    const void* W = d_in[1];
    const void* b = d_in[2];

    char* wsb = (char*)d_ws;
    int* flag            = (int*)wsb;                          // 16 B
    float* bconv         = (float*)(wsb + 16);                 // 6 KB
    unsigned short* xc   = (unsigned short*)(wsb + 16384);     // 32 MB
    unsigned short* Wc   = (unsigned short*)(wsb + 16384 + 33554432);  // 1.5 MB
    h2* plv              = (h2*)(wsb + 36700160);              // 64 MB packed (lf,lv)
    float* Asum          = (float*)(wsb + 36700160 + 67108864);// 512 KB
    float* Bval          = Asum + (size_t)NBATCH * NC * H_DIM;

    fused_convert<<<8577, 256, 0, stream>>>(x, W, b, xc, Wc, bconv, flag);

    dim3 g1(H_DIM / 64, M_TOTAL / BM);   // (8, 256)
    gemm_gates<<<g1, 256, 0, stream>>>(xc, Wc, bconv, plv);

    dim3 g2(H_DIM / 256, NC, NBATCH);    // (2, 32, 8)
    scan_chunks<<<g2, 256, 0, stream>>>(plv, Asum, Bval);
    scan_apply<<<g2, 256, 0, stream>>>(plv, Asum, Bval, d_out, flag);
}

// Round 5
// 326.976 us; speedup vs baseline: 1.4835x; 1.4835x over previous
//
#include <hip/hip_runtime.h>
#include <hip/hip_bf16.h>

// minLSTM: pre = x @ W^T + b (M=32768, N=1536, K=512), log-space gates,
// chunked log-space scan over L=4096 per (n,h), out = exp(log_h).
// Inputs detected fp32-vs-bf16 on device; normalized to bf16 for MFMA.
// GEMM block (bx,by) == scan chunk (n=by>>5, c=by&31, cols bx*64..+64):
// chunk summaries (Asum,Bval) are computed in the GEMM epilogue tail.

#define H_DIM 512
#define LSEQ 4096
#define NBATCH 8
#define M_TOTAL (NBATCH * LSEQ)  // 32768

#define BM 128
#define BK 64

#define CS 128
#define NC 32            // LSEQ / CS

typedef __attribute__((ext_vector_type(8))) short short8;
typedef __attribute__((ext_vector_type(4))) float floatx4;
typedef _Float16 h2 __attribute__((ext_vector_type(2)));

#define NEG_BIG (-1.0e30f)

__device__ __forceinline__ float softplus_f(float z) {
    return fmaxf(z, 0.0f) + __logf(1.0f + __expf(-fabsf(z)));
}

__device__ __forceinline__ float logaddexp_f(float p, float q) {
    float m = fmaxf(p, q);
    float d = -fabsf(p - q);
    return m + __logf(1.0f + __expf(d));
}

__device__ __forceinline__ float bf16u_to_f(unsigned short u) {
    unsigned int w = ((unsigned int)u) << 16;
    float f;
    __builtin_memcpy(&f, &w, 4);
    return f;
}

__device__ __forceinline__ unsigned short f_to_bf16u(float f) {
    __hip_bfloat16 h = __float2bfloat16(f);
    unsigned short u;
    __builtin_memcpy(&u, &h, 2);
    return u;
}

__device__ __forceinline__ void gload_lds16(const void* g, void* l) {
    __builtin_amdgcn_global_load_lds(
        (const __attribute__((address_space(1))) unsigned int*)g,
        (__attribute__((address_space(3))) unsigned int*)l, 16, 0, 0);
}

// ---------------------------------------------------------------------------
// Kernel 0 (fused): per-block self-detection of input dtype (fp32 vs bf16)
// from the same L2-hot 32KB sample of x, then role by blockIdx:
//   [0, 8192) convert x ; [8192, 8576) convert W ; 8576 bias + flag
// ---------------------------------------------------------------------------
__global__ __launch_bounds__(256)
void fused_convert(const void* __restrict__ x, const void* __restrict__ W,
                   const void* __restrict__ bsrc,
                   unsigned short* __restrict__ xc,
                   unsigned short* __restrict__ Wc,
                   float* __restrict__ bdst,
                   int* __restrict__ flagOut) {
    const unsigned short* xu = (const unsigned short*)x;
    __shared__ int cnt;
    if (threadIdx.x == 0) cnt = 0;
    __syncthreads();
    int local = 0;
    for (int i = threadIdx.x; i < 16384; i += 256) {
        unsigned short u = xu[i];
        if (((u >> 7) & 0xFF) == 0xFF) local++;
    }
    if (local) atomicAdd(&cnt, local);
    __syncthreads();
    const int flag = (cnt > 8) ? 1 : 0;

    const int bx = blockIdx.x;
    if (bx < 8192) {                       // x: 16777216 elems
        int i = (bx * 256 + threadIdx.x) * 8;
        if (flag) {
            const float* s = (const float*)x;
            short8 v;
            #pragma unroll
            for (int j = 0; j < 8; j++) v[j] = (short)f_to_bf16u(s[i + j]);
            *(short8*)&xc[i] = v;
        } else {
            *(short8*)&xc[i] = *(const short8*)&((const short*)x)[i];
        }
    } else if (bx < 8576) {                // W: 786432 elems
        int i = ((bx - 8192) * 256 + threadIdx.x) * 8;
        if (flag) {
            const float* s = (const float*)W;
            short8 v;
            #pragma unroll
            for (int j = 0; j < 8; j++) v[j] = (short)f_to_bf16u(s[i + j]);
            *(short8*)&Wc[i] = v;
        } else {
            *(short8*)&Wc[i] = *(const short8*)&((const short*)W)[i];
        }
    } else {                               // bias + flag
        for (int i = threadIdx.x; i < 3 * H_DIM; i += 256)
            bdst[i] = flag ? ((const float*)bsrc)[i]
                           : bf16u_to_f(((const unsigned short*)bsrc)[i]);
        if (threadIdx.x == 0) flagOut[0] = flag;
    }
}

// ---------------------------------------------------------------------------
// Kernel 1: GEMM + gate math + fused per-chunk scan summary.
// Block 256 = 4 waves (2x2). global_load_lds width-16 staging.
// LDS XOR swizzle (verified: SQ_LDS_BANK_CONFLICT = 0).
// After K-loop, (lf,lv) go to LDS (reusing staging buffer) and wave 0
// computes the chunk summary (Asum = sum lf, Bval = local scan).
// ---------------------------------------------------------------------------
__global__ __launch_bounds__(256, 2)
void gemm_gates(const unsigned short* __restrict__ x,
                const unsigned short* __restrict__ W,
                const float* __restrict__ bias,
                h2* __restrict__ plv,
                float* __restrict__ Asum,
                float* __restrict__ Bval) {
    __shared__ __align__(16) char ldsbuf[40960];
    short* Alds = (short*)ldsbuf;              // 16 KB during K-loop
    short* Blds = (short*)(ldsbuf + 16384);    // 24 KB during K-loop
    h2* sc = (h2*)ldsbuf;                      // 32 KB after K-loop

    const int bx = blockIdx.x;             // col block 0..7 (64 cols/gate)
    const int by = blockIdx.y;             // row block 0..255
    const int tid = threadIdx.x;
    const int lane = tid & 63;
    const int w = tid >> 6;
    const int wr = (w >> 1) * 64;
    const int wc2 = w & 1;
    const int l8 = lane >> 3, s8 = lane & 7;
    const int sg = s8 ^ l8;                // swizzled global seg for staging
    const int fr = lane & 15;
    const int q = lane >> 4;

    const int R0 = by * BM;

    floatx4 acc[4][6];
    #pragma unroll
    for (int i = 0; i < 4; i++)
        #pragma unroll
        for (int j = 0; j < 6; j++)
            acc[i][j] = (floatx4){0.f, 0.f, 0.f, 0.f};

    const short* xg = (const short*)x;
    const short* wg = (const short*)W;

    for (int k0 = 0; k0 < H_DIM; k0 += BK) {
        __syncthreads();
        // A: 16 chunks of 8 rows; lane fetches global seg (s8 ^ l8)
        #pragma unroll
        for (int i = 0; i < 4; i++) {
            int c = w * 4 + i;
            const short* g = xg + (size_t)(R0 + c * 8 + l8) * H_DIM + k0 + sg * 8;
            gload_lds16(g, &Alds[c * 512]);
        }
        // B: 24 chunks of 8 rows; row br -> W row (br>>6)*512 + bx*64 + (br&63)
        #pragma unroll
        for (int i = 0; i < 6; i++) {
            int c = w * 6 + i;
            int br = c * 8 + l8;
            int wrow = (br >> 6) * H_DIM + bx * 64 + (br & 63);
            const short* g = wg + (size_t)wrow * H_DIM + k0 + sg * 8;
            gload_lds16(g, &Blds[c * 512]);
        }
        __syncthreads();

        #pragma unroll
        for (int ks = 0; ks < 2; ks++) {
            const int s = ks * 4 + q;       // k-seg index
            short8 af[4], bf[6];
            #pragma unroll
            for (int mt = 0; mt < 4; mt++) {
                int ar = wr + mt * 16 + fr;
                af[mt] = *(const short8*)&Alds[ar * BK + ((s ^ (ar & 7)) << 3)];
            }
            #pragma unroll
            for (int j = 0; j < 6; j++) {
                int nt = (j >> 1) * 4 + wc2 * 2 + (j & 1);
                int brr = nt * 16 + fr;
                bf[j] = *(const short8*)&Blds[brr * BK + ((s ^ (brr & 7)) << 3)];
            }
            #pragma unroll
            for (int mt = 0; mt < 4; mt++)
                #pragma unroll
                for (int j = 0; j < 6; j++)
                    acc[mt][j] = __builtin_amdgcn_mfma_f32_16x16x32_bf16(
                        af[mt], bf[j], acc[mt][j], 0, 0, 0);
        }
    }

    __syncthreads();   // all waves done reading staging LDS; safe to reuse as sc

    // Epilogue: C/D layout col=lane&15, row=quad*4+reg [m89/m91].
    // li = -sp(-diff) = diff + lf (identity; saves one softplus)
    const int rowb = R0 + wr + q * 4;
    const int tloc0 = wr + q * 4;          // local t within chunk
    #pragma unroll
    for (int jj = 0; jj < 2; jj++) {
        int hl = wc2 * 32 + jj * 16 + fr;  // local col 0..63
        int hcol = bx * 64 + hl;
        float bfv = bias[hcol];
        float biv = bias[H_DIM + hcol];
        float bhv = bias[2 * H_DIM + hcol];
        #pragma unroll
        for (int mt = 0; mt < 4; mt++) {
            #pragma unroll
            for (int r = 0; r < 4; r++) {
                float fp = acc[mt][jj][r] + bfv;
                float ip = acc[mt][2 + jj][r] + biv;
                float hp = acc[mt][4 + jj][r] + bhv;
                float diff = softplus_f(-fp) - softplus_f(-ip);
                float lf = -softplus_f(diff);            // log f'
                float li = diff + lf;                    // log i'
                float lg = (hp >= 0.f) ? __logf(hp + 0.5f) : -softplus_f(-hp);
                float lv = li + lg;
                int row = rowb + mt * 16 + r;
                h2 pk;
                pk[0] = (_Float16)lf;
                pk[1] = (_Float16)lv;
                plv[(size_t)row * H_DIM + hcol] = pk;
                sc[(tloc0 + mt * 16 + r) * 64 + hl] = pk;
            }
        }
    }

    __syncthreads();

    // Wave 0: serial chunk scan per column (128 steps). Column reads are
    // addr = t*256B + lane*4B -> 2 lanes/bank (free).
    if (w == 0) {
        float a = 0.f;
        float bacc = NEG_BIG;
        #pragma unroll 4
        for (int t = 0; t < CS; t++) {
            h2 p = sc[t * 64 + lane];
            float f = (float)p[0];
            bacc = logaddexp_f(f + bacc, (float)p[1]);
            a += f;
        }
        int n = by >> 5, c = by & 31;
        size_t o = ((size_t)n * NC + c) * H_DIM + bx * 64 + lane;
        Asum[o] = a;
        Bval[o] = bacc;
    }
}

// ---------------------------------------------------------------------------
// Kernel 2: recompute carry from chunk summaries (<=31 logaddexp steps),
// then replay chunk and write exp(log_h) (dtype per flag).
// ---------------------------------------------------------------------------
__global__ __launch_bounds__(256)
void scan_apply(const h2* __restrict__ plv,
                const float* __restrict__ Asum, const float* __restrict__ Bval,
                void* __restrict__ outv, const int* __restrict__ flag) {
    int h = blockIdx.x * 256 + threadIdx.x;
    int c = blockIdx.y;
    int n = blockIdx.z;
    const int f32out = *flag;

    float r = -13.815510558f;  // log(1e-6)
    size_t so = (size_t)n * NC * H_DIM + h;
    for (int cp = 0; cp < c; cp++)
        r = logaddexp_f(Asum[so + (size_t)cp * H_DIM] + r,
                        Bval[so + (size_t)cp * H_DIM]);

    size_t base = ((size_t)n * LSEQ + (size_t)c * CS) * H_DIM + h;
    float* of = (float*)outv;
    __hip_bfloat16* ob = (__hip_bfloat16*)outv;
    #pragma unroll 4
    for (int t = 0; t < CS; t++) {
        h2 p = plv[base + (size_t)t * H_DIM];
        r = logaddexp_f((float)p[0] + r, (float)p[1]);
        float hval = __expf(r);
        size_t idx = base + (size_t)t * H_DIM;
        if (f32out) of[idx] = hval;
        else        ob[idx] = __float2bfloat16(hval);
    }
}

extern "C" void kernel_launch(void* const* d_in, const int* in_sizes, int n_in,
                              void* d_out, int out_size, void* d_ws, size_t ws_size,
                              hipStream_t stream) {
    const void* x = d_in[0];
    const void* W = d_in[1];
    const void* b = d_in[2];

    char* wsb = (char*)d_ws;
    int* flag            = (int*)wsb;                          // 16 B
    float* bconv         = (float*)(wsb + 16);                 // 6 KB
    unsigned short* xc   = (unsigned short*)(wsb + 16384);     // 32 MB
    unsigned short* Wc   = (unsigned short*)(wsb + 16384 + 33554432);  // 1.5 MB
    h2* plv              = (h2*)(wsb + 36700160);              // 64 MB packed (lf,lv)
    float* Asum          = (float*)(wsb + 36700160 + 67108864);// 512 KB
    float* Bval          = Asum + (size_t)NBATCH * NC * H_DIM;

    fused_convert<<<8577, 256, 0, stream>>>(x, W, b, xc, Wc, bconv, flag);

    dim3 g1(H_DIM / 64, M_TOTAL / BM);   // (8, 256)
    gemm_gates<<<g1, 256, 0, stream>>>(xc, Wc, bconv, plv, Asum, Bval);

    dim3 g2(H_DIM / 256, NC, NBATCH);    // (2, 32, 8)
    scan_apply<<<g2, 256, 0, stream>>>(plv, Asum, Bval, d_out, flag);
}

// Round 6
// 317.233 us; speedup vs baseline: 1.5291x; 1.0307x over previous
//
#include <hip/hip_runtime.h>
#include <hip/hip_bf16.h>

// minLSTM: pre = x @ W^T + b (M=32768, N=1536, K=512), log-space gates,
// chunked log-space scan over L=4096 per (n,h), out = exp(log_h).
// Inputs detected fp32-vs-bf16 on device; normalized to bf16 for MFMA.
// GEMM block (bx,by) == scan chunk (n=by>>5, c=by&31, cols bx*64..+64):
// chunk summaries (Asum,Bval) computed in a PARALLEL gemm epilogue tail
// (4 waves scan 32-t sub-segments; wave 0 folds them — scan op is associative).

#define H_DIM 512
#define LSEQ 4096
#define NBATCH 8
#define M_TOTAL (NBATCH * LSEQ)  // 32768

#define BM 128
#define BK 64

#define CS 128
#define NC 32            // LSEQ / CS

typedef __attribute__((ext_vector_type(8))) short short8;
typedef __attribute__((ext_vector_type(4))) float floatx4;
typedef _Float16 h2 __attribute__((ext_vector_type(2)));
typedef _Float16 h4 __attribute__((ext_vector_type(4)));
typedef __attribute__((ext_vector_type(2))) float float2v;

#define NEG_BIG (-1.0e30f)

__device__ __forceinline__ float softplus_f(float z) {
    return fmaxf(z, 0.0f) + __logf(1.0f + __expf(-fabsf(z)));
}

__device__ __forceinline__ float logaddexp_f(float p, float q) {
    float m = fmaxf(p, q);
    float d = -fabsf(p - q);
    return m + __logf(1.0f + __expf(d));
}

__device__ __forceinline__ float bf16u_to_f(unsigned short u) {
    unsigned int w = ((unsigned int)u) << 16;
    float f;
    __builtin_memcpy(&f, &w, 4);
    return f;
}

__device__ __forceinline__ unsigned short f_to_bf16u(float f) {
    __hip_bfloat16 h = __float2bfloat16(f);
    unsigned short u;
    __builtin_memcpy(&u, &h, 2);
    return u;
}

__device__ __forceinline__ void gload_lds16(const void* g, void* l) {
    __builtin_amdgcn_global_load_lds(
        (const __attribute__((address_space(1))) unsigned int*)g,
        (__attribute__((address_space(3))) unsigned int*)l, 16, 0, 0);
}

// ---------------------------------------------------------------------------
// Kernel 0 (fused): per-block self-detection of input dtype (fp32 vs bf16)
// from the same L2-hot 32KB sample of x, then role by blockIdx:
//   [0, 8192) convert x ; [8192, 8576) convert W ; 8576 bias + flag
// ---------------------------------------------------------------------------
__global__ __launch_bounds__(256)
void fused_convert(const void* __restrict__ x, const void* __restrict__ W,
                   const void* __restrict__ bsrc,
                   unsigned short* __restrict__ xc,
                   unsigned short* __restrict__ Wc,
                   float* __restrict__ bdst,
                   int* __restrict__ flagOut) {
    const unsigned short* xu = (const unsigned short*)x;
    __shared__ int cnt;
    if (threadIdx.x == 0) cnt = 0;
    __syncthreads();
    int local = 0;
    for (int i = threadIdx.x; i < 16384; i += 256) {
        unsigned short u = xu[i];
        if (((u >> 7) & 0xFF) == 0xFF) local++;
    }
    if (local) atomicAdd(&cnt, local);
    __syncthreads();
    const int flag = (cnt > 8) ? 1 : 0;

    const int bx = blockIdx.x;
    if (bx < 8192) {                       // x: 16777216 elems
        int i = (bx * 256 + threadIdx.x) * 8;
        if (flag) {
            const float* s = (const float*)x;
            short8 v;
            #pragma unroll
            for (int j = 0; j < 8; j++) v[j] = (short)f_to_bf16u(s[i + j]);
            *(short8*)&xc[i] = v;
        } else {
            *(short8*)&xc[i] = *(const short8*)&((const short*)x)[i];
        }
    } else if (bx < 8576) {                // W: 786432 elems
        int i = ((bx - 8192) * 256 + threadIdx.x) * 8;
        if (flag) {
            const float* s = (const float*)W;
            short8 v;
            #pragma unroll
            for (int j = 0; j < 8; j++) v[j] = (short)f_to_bf16u(s[i + j]);
            *(short8*)&Wc[i] = v;
        } else {
            *(short8*)&Wc[i] = *(const short8*)&((const short*)W)[i];
        }
    } else {                               // bias + flag
        for (int i = threadIdx.x; i < 3 * H_DIM; i += 256)
            bdst[i] = flag ? ((const float*)bsrc)[i]
                           : bf16u_to_f(((const unsigned short*)bsrc)[i]);
        if (threadIdx.x == 0) flagOut[0] = flag;
    }
}

// ---------------------------------------------------------------------------
// Kernel 1: GEMM + gate math + fused per-chunk scan summary (parallel tail).
// Block 256 = 4 waves (2x2). global_load_lds width-16 staging.
// LDS XOR swizzle (verified: bank conflicts ~0).
// ---------------------------------------------------------------------------
__global__ __launch_bounds__(256, 2)
void gemm_gates(const unsigned short* __restrict__ x,
                const unsigned short* __restrict__ W,
                const float* __restrict__ bias,
                h2* __restrict__ plv,
                float* __restrict__ Asum,
                float* __restrict__ Bval) {
    __shared__ __align__(16) char ldsbuf[40960];
    short* Alds = (short*)ldsbuf;              // 16 KB during K-loop
    short* Blds = (short*)(ldsbuf + 16384);    // 24 KB during K-loop
    h2* sc = (h2*)ldsbuf;                      // 32 KB after K-loop
    float* sa = (float*)(ldsbuf + 32768);      // 1 KB sub-summary A
    float* sb = sa + 256;                      // 1 KB sub-summary B

    const int bx = blockIdx.x;             // col block 0..7 (64 cols/gate)
    const int by = blockIdx.y;             // row block 0..255
    const int tid = threadIdx.x;
    const int lane = tid & 63;
    const int w = tid >> 6;
    const int wr = (w >> 1) * 64;
    const int wc2 = w & 1;
    const int l8 = lane >> 3, s8 = lane & 7;
    const int sg = s8 ^ l8;                // swizzled global seg for staging
    const int fr = lane & 15;
    const int q = lane >> 4;

    const int R0 = by * BM;

    floatx4 acc[4][6];
    #pragma unroll
    for (int i = 0; i < 4; i++)
        #pragma unroll
        for (int j = 0; j < 6; j++)
            acc[i][j] = (floatx4){0.f, 0.f, 0.f, 0.f};

    const short* xg = (const short*)x;
    const short* wg = (const short*)W;

    for (int k0 = 0; k0 < H_DIM; k0 += BK) {
        __syncthreads();
        // A: 16 chunks of 8 rows; lane fetches global seg (s8 ^ l8)
        #pragma unroll
        for (int i = 0; i < 4; i++) {
            int c = w * 4 + i;
            const short* g = xg + (size_t)(R0 + c * 8 + l8) * H_DIM + k0 + sg * 8;
            gload_lds16(g, &Alds[c * 512]);
        }
        // B: 24 chunks of 8 rows; row br -> W row (br>>6)*512 + bx*64 + (br&63)
        #pragma unroll
        for (int i = 0; i < 6; i++) {
            int c = w * 6 + i;
            int br = c * 8 + l8;
            int wrow = (br >> 6) * H_DIM + bx * 64 + (br & 63);
            const short* g = wg + (size_t)wrow * H_DIM + k0 + sg * 8;
            gload_lds16(g, &Blds[c * 512]);
        }
        __syncthreads();

        #pragma unroll
        for (int ks = 0; ks < 2; ks++) {
            const int s = ks * 4 + q;       // k-seg index
            short8 af[4], bf[6];
            #pragma unroll
            for (int mt = 0; mt < 4; mt++) {
                int ar = wr + mt * 16 + fr;
                af[mt] = *(const short8*)&Alds[ar * BK + ((s ^ (ar & 7)) << 3)];
            }
            #pragma unroll
            for (int j = 0; j < 6; j++) {
                int nt = (j >> 1) * 4 + wc2 * 2 + (j & 1);
                int brr = nt * 16 + fr;
                bf[j] = *(const short8*)&Blds[brr * BK + ((s ^ (brr & 7)) << 3)];
            }
            #pragma unroll
            for (int mt = 0; mt < 4; mt++)
                #pragma unroll
                for (int j = 0; j < 6; j++)
                    acc[mt][j] = __builtin_amdgcn_mfma_f32_16x16x32_bf16(
                        af[mt], bf[j], acc[mt][j], 0, 0, 0);
        }
    }

    __syncthreads();   // staging LDS dead; reuse as sc

    // Epilogue: C/D layout col=lane&15, row=quad*4+reg [m89/m91].
    // li = -sp(-diff) = diff + lf (identity; saves one softplus)
    const int rowb = R0 + wr + q * 4;
    const int tloc0 = wr + q * 4;          // local t within chunk
    #pragma unroll
    for (int jj = 0; jj < 2; jj++) {
        int hl = wc2 * 32 + jj * 16 + fr;  // local col 0..63
        int hcol = bx * 64 + hl;
        float bfv = bias[hcol];
        float biv = bias[H_DIM + hcol];
        float bhv = bias[2 * H_DIM + hcol];
        #pragma unroll
        for (int mt = 0; mt < 4; mt++) {
            #pragma unroll
            for (int r = 0; r < 4; r++) {
                float fp = acc[mt][jj][r] + bfv;
                float ip = acc[mt][2 + jj][r] + biv;
                float hp = acc[mt][4 + jj][r] + bhv;
                float diff = softplus_f(-fp) - softplus_f(-ip);
                float lf = -softplus_f(diff);            // log f'
                float li = diff + lf;                    // log i'
                float lg = (hp >= 0.f) ? __logf(hp + 0.5f) : -softplus_f(-hp);
                float lv = li + lg;
                int row = rowb + mt * 16 + r;
                h2 pk;
                pk[0] = (_Float16)lf;
                pk[1] = (_Float16)lv;
                plv[(size_t)row * H_DIM + hcol] = pk;
                sc[(tloc0 + mt * 16 + r) * 64 + hl] = pk;
            }
        }
    }

    __syncthreads();

    // Parallel chunk summary: wave w scans t in [w*32, w*32+32) for col=lane.
    // sc column reads: stride 256B, lane*4B -> 2 lanes/bank (free).
    {
        float a = 0.f, bacc = NEG_BIG;
        const int t0 = w * 32;
        #pragma unroll 4
        for (int t = t0; t < t0 + 32; t++) {
            h2 p = sc[t * 64 + lane];
            float f = (float)p[0];
            bacc = logaddexp_f(f + bacc, (float)p[1]);
            a += f;
        }
        sa[w * 64 + lane] = a;
        sb[w * 64 + lane] = bacc;
    }
    __syncthreads();

    if (w == 0) {
        float a = sa[lane], b = sb[lane];
        #pragma unroll
        for (int s = 1; s < 4; s++) {
            float as = sa[s * 64 + lane], bs = sb[s * 64 + lane];
            b = logaddexp_f(as + b, bs);
            a += as;
        }
        int n = by >> 5, c = by & 31;
        size_t o = ((size_t)n * NC + c) * H_DIM + bx * 64 + lane;
        Asum[o] = a;
        Bval[o] = b;
    }
}

// ---------------------------------------------------------------------------
// Kernel 2: recompute carry from chunk summaries (<=31 logaddexp steps),
// then replay chunk and write exp(log_h). 2 h-columns per thread, 8B loads.
// grid (NC, NBATCH), block 256 (covers all 512 h).
// ---------------------------------------------------------------------------
__global__ __launch_bounds__(256)
void scan_apply(const h2* __restrict__ plv,
                const float* __restrict__ Asum, const float* __restrict__ Bval,
                void* __restrict__ outv, const int* __restrict__ flag) {
    const int c = blockIdx.x;
    const int n = blockIdx.y;
    const int h0 = threadIdx.x * 2;
    const int f32out = *flag;

    float r0 = -13.815510558f;  // log(1e-6)
    float r1 = r0;
    size_t so = (size_t)n * NC * H_DIM + h0;
    for (int cp = 0; cp < c; cp++) {
        float2v A = *(const float2v*)&Asum[so + (size_t)cp * H_DIM];
        float2v B = *(const float2v*)&Bval[so + (size_t)cp * H_DIM];
        r0 = logaddexp_f(A[0] + r0, B[0]);
        r1 = logaddexp_f(A[1] + r1, B[1]);
    }

    size_t base = ((size_t)n * LSEQ + (size_t)c * CS) * H_DIM + h0;
    float* of = (float*)outv;
    unsigned int* ob32 = (unsigned int*)outv;
    #pragma unroll 4
    for (int t = 0; t < CS; t++) {
        size_t idx = base + (size_t)t * H_DIM;
        h4 p = *(const h4*)&plv[idx];          // (lf0, lv0, lf1, lv1)
        r0 = logaddexp_f((float)p[0] + r0, (float)p[1]);
        r1 = logaddexp_f((float)p[2] + r1, (float)p[3]);
        float e0 = __expf(r0), e1 = __expf(r1);
        if (f32out) {
            float2v o2 = {e0, e1};
            *(float2v*)&of[idx] = o2;
        } else {
            unsigned int pk = ((unsigned int)f_to_bf16u(e1) << 16) | f_to_bf16u(e0);
            ob32[idx >> 1] = pk;
        }
    }
}

extern "C" void kernel_launch(void* const* d_in, const int* in_sizes, int n_in,
                              void* d_out, int out_size, void* d_ws, size_t ws_size,
                              hipStream_t stream) {
    const void* x = d_in[0];
    const void* W = d_in[1];
    const void* b = d_in[2];

    char* wsb = (char*)d_ws;
    int* flag            = (int*)wsb;                          // 16 B
    float* bconv         = (float*)(wsb + 16);                 // 6 KB
    unsigned short* xc   = (unsigned short*)(wsb + 16384);     // 32 MB
    unsigned short* Wc   = (unsigned short*)(wsb + 16384 + 33554432);  // 1.5 MB
    h2* plv              = (h2*)(wsb + 36700160);              // 64 MB packed (lf,lv)
    float* Asum          = (float*)(wsb + 36700160 + 67108864);// 512 KB
    float* Bval          = Asum + (size_t)NBATCH * NC * H_DIM;

    fused_convert<<<8577, 256, 0, stream>>>(x, W, b, xc, Wc, bconv, flag);

    dim3 g1(H_DIM / 64, M_TOTAL / BM);   // (8, 256)
    gemm_gates<<<g1, 256, 0, stream>>>(xc, Wc, bconv, plv, Asum, Bval);

    dim3 g2(NC, NBATCH);                 // (32, 8)
    scan_apply<<<g2, 256, 0, stream>>>(plv, Asum, Bval, d_out, flag);
}

// Round 7
// 269.545 us; speedup vs baseline: 1.7996x; 1.1769x over previous
//
#include <hip/hip_runtime.h>
#include <hip/hip_bf16.h>

// minLSTM: pre = x @ W^T + b (M=32768, N=1536, K=512), log-space gates,
// chunked log-space scan over L=4096 per (n,h), out = exp(log_h).
// Inputs detected fp32-vs-bf16 on device once; converts read the flag.
// GEMM block (bx,by) == scan chunk (n=by>>5, c=by&31, cols bx*64..+64).
// GEMM tail emits per-32-t sub-summaries (Asub/Bsub) AND chunk summaries
// (Asum/Bval); scan_apply runs at 32-t granularity for 4x parallelism.

#define H_DIM 512
#define LSEQ 4096
#define NBATCH 8
#define M_TOTAL (NBATCH * LSEQ)  // 32768

#define BM 128
#define BK 64

#define CS 128
#define NC 32            // LSEQ / CS

typedef __attribute__((ext_vector_type(8))) short short8;
typedef __attribute__((ext_vector_type(4))) float floatx4;
typedef __attribute__((ext_vector_type(4))) float float4v;
typedef _Float16 h2 __attribute__((ext_vector_type(2)));
typedef _Float16 h4 __attribute__((ext_vector_type(4)));
typedef __attribute__((ext_vector_type(2))) float float2v;

#define NEG_BIG (-1.0e30f)

__device__ __forceinline__ float softplus_f(float z) {
    return fmaxf(z, 0.0f) + __logf(1.0f + __expf(-fabsf(z)));
}

__device__ __forceinline__ float logaddexp_f(float p, float q) {
    float m = fmaxf(p, q);
    float d = -fabsf(p - q);
    return m + __logf(1.0f + __expf(d));
}

__device__ __forceinline__ float bf16u_to_f(unsigned short u) {
    unsigned int w = ((unsigned int)u) << 16;
    float f;
    __builtin_memcpy(&f, &w, 4);
    return f;
}

__device__ __forceinline__ unsigned short f_to_bf16u(float f) {
    __hip_bfloat16 h = __float2bfloat16(f);
    unsigned short u;
    __builtin_memcpy(&u, &h, 2);
    return u;
}

__device__ __forceinline__ void gload_lds16(const void* g, void* l) {
    __builtin_amdgcn_global_load_lds(
        (const __attribute__((address_space(1))) unsigned int*)g,
        (__attribute__((address_space(3))) unsigned int*)l, 16, 0, 0);
}

// ---------------------------------------------------------------------------
// Kernel 0: dtype detect (single block) + bias -> f32.
// fp32 data: low u16 halves uniform -> bf16-NaN exponent P=1/256,
// E[hits in 16384] = 64; bf16 N(0,1) data: 0 hits.
// ---------------------------------------------------------------------------
__global__ void detect_and_bias(const unsigned short* __restrict__ xu,
                                const void* __restrict__ bsrc,
                                int* __restrict__ flag,
                                float* __restrict__ bdst) {
    __shared__ int cnt;
    if (threadIdx.x == 0) cnt = 0;
    __syncthreads();
    int local = 0;
    for (int i = threadIdx.x; i < 16384; i += 256) {
        unsigned short u = xu[i];
        if (((u >> 7) & 0xFF) == 0xFF) local++;
    }
    if (local) atomicAdd(&cnt, local);
    __syncthreads();
    int f = (cnt > 8) ? 1 : 0;
    if (threadIdx.x == 0) flag[0] = f;
    for (int i = threadIdx.x; i < 3 * H_DIM; i += 256)
        bdst[i] = f ? ((const float*)bsrc)[i]
                    : bf16u_to_f(((const unsigned short*)bsrc)[i]);
}

// ---------------------------------------------------------------------------
// Kernel 0b: normalize x and W to bf16 (role by block range). Vector loads.
//   [0, 8192) -> x (16777216 elems), [8192, 8576) -> W (786432 elems)
// ---------------------------------------------------------------------------
__global__ __launch_bounds__(256)
void convert_inputs(const void* __restrict__ x, const void* __restrict__ W,
                    unsigned short* __restrict__ xc,
                    unsigned short* __restrict__ Wc,
                    const int* __restrict__ flag) {
    const int bx = blockIdx.x;
    const void* src;
    unsigned short* dst;
    int i;
    if (bx < 8192) { src = x; dst = xc; i = (bx * 256 + threadIdx.x) * 8; }
    else           { src = W; dst = Wc; i = ((bx - 8192) * 256 + threadIdx.x) * 8; }
    if (*flag) {
        const float4v* s4 = (const float4v*)((const float*)src + i);
        float4v a = s4[0], b = s4[1];
        short8 v;
        v[0] = (short)f_to_bf16u(a[0]); v[1] = (short)f_to_bf16u(a[1]);
        v[2] = (short)f_to_bf16u(a[2]); v[3] = (short)f_to_bf16u(a[3]);
        v[4] = (short)f_to_bf16u(b[0]); v[5] = (short)f_to_bf16u(b[1]);
        v[6] = (short)f_to_bf16u(b[2]); v[7] = (short)f_to_bf16u(b[3]);
        *(short8*)&dst[i] = v;
    } else {
        *(short8*)&dst[i] = *(const short8*)&((const short*)src)[i];
    }
}

// ---------------------------------------------------------------------------
// Kernel 1: GEMM + gate math + fused scan summaries.
// Block 256 = 4 waves (2x2). global_load_lds width-16 staging.
// LDS XOR swizzle (verified: conflicts ~0). Tail: wave w scans its 32-t
// sub-segment -> Asub/Bsub (global) + LDS; wave 0 folds 4 -> Asum/Bval.
// ---------------------------------------------------------------------------
__global__ __launch_bounds__(256, 3)
void gemm_gates(const unsigned short* __restrict__ x,
                const unsigned short* __restrict__ W,
                const float* __restrict__ bias,
                h2* __restrict__ plv,
                float* __restrict__ Asum, float* __restrict__ Bval,
                float* __restrict__ Asub, float* __restrict__ Bsub) {
    __shared__ __align__(16) char ldsbuf[40960];
    short* Alds = (short*)ldsbuf;              // 16 KB during K-loop
    short* Blds = (short*)(ldsbuf + 16384);    // 24 KB during K-loop
    h2* sc = (h2*)ldsbuf;                      // 32 KB after K-loop
    float* sa = (float*)(ldsbuf + 32768);      // 1 KB sub-summary A
    float* sb = sa + 256;                      // 1 KB sub-summary B

    const int bx = blockIdx.x;             // col block 0..7 (64 cols/gate)
    const int by = blockIdx.y;             // row block 0..255
    const int tid = threadIdx.x;
    const int lane = tid & 63;
    const int w = tid >> 6;
    const int wr = (w >> 1) * 64;
    const int wc2 = w & 1;
    const int l8 = lane >> 3, s8 = lane & 7;
    const int sg = s8 ^ l8;                // swizzled global seg for staging
    const int fr = lane & 15;
    const int q = lane >> 4;

    const int R0 = by * BM;

    floatx4 acc[4][6];
    #pragma unroll
    for (int i = 0; i < 4; i++)
        #pragma unroll
        for (int j = 0; j < 6; j++)
            acc[i][j] = (floatx4){0.f, 0.f, 0.f, 0.f};

    const short* xg = (const short*)x;
    const short* wg = (const short*)W;

    for (int k0 = 0; k0 < H_DIM; k0 += BK) {
        __syncthreads();
        #pragma unroll
        for (int i = 0; i < 4; i++) {
            int c = w * 4 + i;
            const short* g = xg + (size_t)(R0 + c * 8 + l8) * H_DIM + k0 + sg * 8;
            gload_lds16(g, &Alds[c * 512]);
        }
        #pragma unroll
        for (int i = 0; i < 6; i++) {
            int c = w * 6 + i;
            int br = c * 8 + l8;
            int wrow = (br >> 6) * H_DIM + bx * 64 + (br & 63);
            const short* g = wg + (size_t)wrow * H_DIM + k0 + sg * 8;
            gload_lds16(g, &Blds[c * 512]);
        }
        __syncthreads();

        #pragma unroll
        for (int ks = 0; ks < 2; ks++) {
            const int s = ks * 4 + q;
            short8 af[4], bf[6];
            #pragma unroll
            for (int mt = 0; mt < 4; mt++) {
                int ar = wr + mt * 16 + fr;
                af[mt] = *(const short8*)&Alds[ar * BK + ((s ^ (ar & 7)) << 3)];
            }
            #pragma unroll
            for (int j = 0; j < 6; j++) {
                int nt = (j >> 1) * 4 + wc2 * 2 + (j & 1);
                int brr = nt * 16 + fr;
                bf[j] = *(const short8*)&Blds[brr * BK + ((s ^ (brr & 7)) << 3)];
            }
            #pragma unroll
            for (int mt = 0; mt < 4; mt++)
                #pragma unroll
                for (int j = 0; j < 6; j++)
                    acc[mt][j] = __builtin_amdgcn_mfma_f32_16x16x32_bf16(
                        af[mt], bf[j], acc[mt][j], 0, 0, 0);
        }
    }

    __syncthreads();   // staging LDS dead; reuse as sc

    // Epilogue: C/D layout col=lane&15, row=quad*4+reg [m89/m91].
    // li = -sp(-diff) = diff + lf (identity; saves one softplus)
    const int rowb = R0 + wr + q * 4;
    const int tloc0 = wr + q * 4;
    #pragma unroll
    for (int jj = 0; jj < 2; jj++) {
        int hl = wc2 * 32 + jj * 16 + fr;
        int hcol = bx * 64 + hl;
        float bfv = bias[hcol];
        float biv = bias[H_DIM + hcol];
        float bhv = bias[2 * H_DIM + hcol];
        #pragma unroll
        for (int mt = 0; mt < 4; mt++) {
            #pragma unroll
            for (int r = 0; r < 4; r++) {
                float fp = acc[mt][jj][r] + bfv;
                float ip = acc[mt][2 + jj][r] + biv;
                float hp = acc[mt][4 + jj][r] + bhv;
                float diff = softplus_f(-fp) - softplus_f(-ip);
                float lf = -softplus_f(diff);            // log f'
                float li = diff + lf;                    // log i'
                float lg = (hp >= 0.f) ? __logf(hp + 0.5f) : -softplus_f(-hp);
                float lv = li + lg;
                int row = rowb + mt * 16 + r;
                h2 pk;
                pk[0] = (_Float16)lf;
                pk[1] = (_Float16)lv;
                plv[(size_t)row * H_DIM + hcol] = pk;
                sc[(tloc0 + mt * 16 + r) * 64 + hl] = pk;
            }
        }
    }

    __syncthreads();

    const int n = by >> 5, c = by & 31;
    // Wave w scans t in [w*32, w*32+32) for col=lane; publish sub-summary.
    {
        float a = 0.f, bacc = NEG_BIG;
        const int t0 = w * 32;
        #pragma unroll 4
        for (int t = t0; t < t0 + 32; t++) {
            h2 p = sc[t * 64 + lane];
            float f = (float)p[0];
            bacc = logaddexp_f(f + bacc, (float)p[1]);
            a += f;
        }
        sa[w * 64 + lane] = a;
        sb[w * 64 + lane] = bacc;
        size_t o = (((size_t)n * NC + c) * 4 + w) * H_DIM + bx * 64 + lane;
        Asub[o] = a;
        Bsub[o] = bacc;
    }
    __syncthreads();

    if (w == 0) {
        float a = sa[lane], b = sb[lane];
        #pragma unroll
        for (int s = 1; s < 4; s++) {
            float as = sa[s * 64 + lane], bs = sb[s * 64 + lane];
            b = logaddexp_f(as + b, bs);
            a += as;
        }
        size_t o = ((size_t)n * NC + c) * H_DIM + bx * 64 + lane;
        Asum[o] = a;
        Bval[o] = b;
    }
}

// ---------------------------------------------------------------------------
// Kernel 2: sub-chunk replay. Block (cc, n): c = cc>>2, s = cc&3.
// Carry = fold of c chunk summaries + s sub-summaries (<=34 steps), then
// replay 32 timesteps. 2 h-cols/thread, 8B loads. grid (128, 8) = 1024 blocks.
// ---------------------------------------------------------------------------
__global__ __launch_bounds__(256)
void scan_apply(const h2* __restrict__ plv,
                const float* __restrict__ Asum, const float* __restrict__ Bval,
                const float* __restrict__ Asub, const float* __restrict__ Bsub,
                void* __restrict__ outv, const int* __restrict__ flag) {
    const int cc = blockIdx.x;          // 0..127
    const int n = blockIdx.y;
    const int c = cc >> 2, s = cc & 3;
    const int h0 = threadIdx.x * 2;
    const int f32out = *flag;

    float r0 = -13.815510558f;  // log(1e-6)
    float r1 = r0;
    size_t so = (size_t)n * NC * H_DIM + h0;
    for (int cp = 0; cp < c; cp++) {
        float2v A = *(const float2v*)&Asum[so + (size_t)cp * H_DIM];
        float2v B = *(const float2v*)&Bval[so + (size_t)cp * H_DIM];
        r0 = logaddexp_f(A[0] + r0, B[0]);
        r1 = logaddexp_f(A[1] + r1, B[1]);
    }
    size_t sub = (((size_t)n * NC + c) * 4) * H_DIM + h0;
    for (int sp = 0; sp < s; sp++) {
        float2v A = *(const float2v*)&Asub[sub + (size_t)sp * H_DIM];
        float2v B = *(const float2v*)&Bsub[sub + (size_t)sp * H_DIM];
        r0 = logaddexp_f(A[0] + r0, B[0]);
        r1 = logaddexp_f(A[1] + r1, B[1]);
    }

    size_t base = ((size_t)n * LSEQ + (size_t)c * CS + s * 32) * H_DIM + h0;
    float* of = (float*)outv;
    unsigned int* ob32 = (unsigned int*)outv;
    #pragma unroll 4
    for (int t = 0; t < 32; t++) {
        size_t idx = base + (size_t)t * H_DIM;
        h4 p = *(const h4*)&plv[idx];          // (lf0, lv0, lf1, lv1)
        r0 = logaddexp_f((float)p[0] + r0, (float)p[1]);
        r1 = logaddexp_f((float)p[2] + r1, (float)p[3]);
        float e0 = __expf(r0), e1 = __expf(r1);
        if (f32out) {
            float2v o2 = {e0, e1};
            *(float2v*)&of[idx] = o2;
        } else {
            unsigned int pk = ((unsigned int)f_to_bf16u(e1) << 16) | f_to_bf16u(e0);
            ob32[idx >> 1] = pk;
        }
    }
}

extern "C" void kernel_launch(void* const* d_in, const int* in_sizes, int n_in,
                              void* d_out, int out_size, void* d_ws, size_t ws_size,
                              hipStream_t stream) {
    const void* x = d_in[0];
    const void* W = d_in[1];
    const void* b = d_in[2];

    char* wsb = (char*)d_ws;
    int* flag            = (int*)wsb;                          // 16 B
    float* bconv         = (float*)(wsb + 16);                 // 6 KB
    unsigned short* xc   = (unsigned short*)(wsb + 16384);     // 32 MB
    unsigned short* Wc   = (unsigned short*)(wsb + 16384 + 33554432);  // 1.5 MB
    h2* plv              = (h2*)(wsb + 36700160);              // 64 MB packed (lf,lv)
    float* Asum          = (float*)(wsb + 103809024);          // 512 KB
    float* Bval          = (float*)(wsb + 104333312);          // 512 KB
    float* Asub          = (float*)(wsb + 104857600);          // 2 MB
    float* Bsub          = (float*)(wsb + 106954752);          // 2 MB

    detect_and_bias<<<1, 256, 0, stream>>>((const unsigned short*)x, b, flag, bconv);
    convert_inputs<<<8576, 256, 0, stream>>>(x, W, xc, Wc, flag);

    dim3 g1(H_DIM / 64, M_TOTAL / BM);   // (8, 256)
    gemm_gates<<<g1, 256, 0, stream>>>(xc, Wc, bconv, plv, Asum, Bval, Asub, Bsub);

    dim3 g2(NC * 4, NBATCH);             // (128, 8)
    scan_apply<<<g2, 256, 0, stream>>>(plv, Asum, Bval, Asub, Bsub, d_out, flag);
}